// Round 13
// baseline (588.893 us; speedup 1.0000x reference)
//
#include <hip/hip_runtime.h>
#include <hip/hip_bf16.h>

typedef float f2  __attribute__((ext_vector_type(2)));
typedef float f4v __attribute__((ext_vector_type(4)));

#ifndef __has_builtin
#define __has_builtin(x) 0
#endif

#define HID   32
#define TLEN  2048
#define BATCH 512
#define NWIN  (TLEN / 8)            /* 8-step x windows */
#define L2E   1.4426950408889634f   /* log2(e) */

__device__ __forceinline__ float fast_rcp(float x) {
#if __has_builtin(__builtin_amdgcn_rcpf)
    return __builtin_amdgcn_rcpf(x);
#else
    return 1.0f / x;
#endif
}
__device__ __forceinline__ float fast_rsq(float x) {
#if __has_builtin(__builtin_amdgcn_rsqf)
    return __builtin_amdgcn_rsqf(x);
#else
    return rsqrtf(x);
#endif
}
__device__ __forceinline__ float fast_exp2(float x) {
#if __has_builtin(__builtin_amdgcn_exp2f)
    return __builtin_amdgcn_exp2f(x);
#else
    return exp2f(x);
#endif
}

// sum of x over lane pairs (l, l^32) WITHOUT touching the DS pipe.
__device__ __forceinline__ float xor32_sum(float x) {
#if __has_builtin(__builtin_amdgcn_permlane32_swap)
    typedef unsigned int u2v __attribute__((ext_vector_type(2)));
    u2v r = __builtin_amdgcn_permlane32_swap(__float_as_uint(x), __float_as_uint(x),
                                             false, false);
    return __uint_as_float(r.x) + __uint_as_float(r.y);
#else
    float a = x, b = x;
    asm("v_permlane32_swap_b32 %0, %1" : "+&v"(a), "+&v"(b));
    return a + b;
#endif
}

// ds_swizzle xor within 32-lane groups (BitMode: offset=(xor<<10)|(or<<5)|and)
#if __has_builtin(__builtin_amdgcn_ds_swizzle)
#define SWZ_XOR(x, XORM) \
    __int_as_float(__builtin_amdgcn_ds_swizzle(__float_as_int(x), ((XORM) << 10) | 0x1F))
#else
#define SWZ_XOR(x, XORM) __shfl_xor((x), (XORM))
#endif

// One wave per block, one batch element per wave.
// Gates: lane l -> output j = l&31, K-half = l>>5 (16-wide partial dot);
//        halves combined with permlane32_swap (VALU, no DS latency on chain).
// q-head: batched every 8 steps from an 8-slot h history ring in LDS.
// x path: round-9 counters showed VGPR_Count=84 ~= exactly the gate
//   weights+gi+biases budget -> the 96-VGPR x double-buffer (and wq4) were
//   in SCRATCH, putting ~200cy VMEM reads on every serial step.
//   Now x lives in LDS: lane l stages ONE dword per 8-step window
//   (word l of [s][arr][c] layout), global_load issued a full window early
//   (T14 issue-early/write-late), ds_write after the buffer is consumed,
//   broadcast ds_read_b128 per step.  Zero x registers, zero scratch.
__global__ __launch_bounds__(64, 1) void gru_fused_kernel(
    const float* __restrict__ acc_g, const float* __restrict__ mag_g,
    const float* __restrict__ W_ih, const float* __restrict__ W_hh,
    const float* __restrict__ b_ih, const float* __restrict__ b_hh,
    const float* __restrict__ Wq, const float* __restrict__ bq,
    float* __restrict__ out)
{
    const int lane = threadIdx.x;
    const int j    = lane & 31;
    const int kb   = (lane >> 5) * 16;   // gate K-half base
    const int b    = blockIdx.x;

    const int tq = lane >> 3;        // q-head: timestep within 8-window
    const int kq = (lane >> 2) & 1;  // q-head: K-half
    const int m  = lane & 3;         // q-head: output component

    __shared__ __align__(16) float hbuf[8 * HID];   // h history ring (1 KB)
    __shared__ __align__(16) float xwin[2][64];     // x windows (512 B)

    // ---- per-lane weight preload (registers), with exp2 pre-scaling ----
    f2 wr[8], wz[8], wn[8];
#pragma unroll
    for (int p = 0; p < 8; ++p) {
        wr[p] = L2E          * *reinterpret_cast<const f2*>(W_hh + (0 * HID + j) * HID + kb + 2 * p);
        wz[p] = L2E          * *reinterpret_cast<const f2*>(W_hh + (1 * HID + j) * HID + kb + 2 * p);
        wn[p] = (2.0f * L2E) * *reinterpret_cast<const f2*>(W_hh + (2 * HID + j) * HID + kb + 2 * p);
    }
    f4v wq4[4];
#pragma unroll
    for (int i = 0; i < 4; ++i)
        wq4[i] = *reinterpret_cast<const f4v*>(Wq + m * HID + kq * 16 + 4 * i);

    // gi weights: r/z HALVED (both K-halves accumulate (W/2)x pre-combine, the
    // permlane sum restores W*x); n-gate gi stays full (added post-combine).
    float wir[6], wiz[6], win[6];
#pragma unroll
    for (int i = 0; i < 6; ++i) {
        wir[i] = 0.5f * L2E * W_ih[(0 * HID + j) * 6 + i];
        wiz[i] = 0.5f * L2E * W_ih[(1 * HID + j) * 6 + i];
        win[i] = 2.0f * L2E * W_ih[(2 * HID + j) * 6 + i];
    }
    const float br_s  = 0.5f * L2E * (b_ih[0 * HID + j] + b_hh[0 * HID + j]);
    const float bz_s  = 0.5f * L2E * (b_ih[1 * HID + j] + b_hh[1 * HID + j]);
    const float bhn_s = L2E * b_hh[2 * HID + j];
    const float bin_s = 2.0f * L2E * b_ih[2 * HID + j];
    const float bqv   = bq[m];

    hbuf[7 * HID + j] = 0.0f;        // h_{-1} = 0 (slot 7)

    const float* accp = acc_g + (size_t)b * TLEN * 3;
    const float* magp = mag_g + (size_t)b * TLEN * 3;
    float* outp = out + (size_t)b * TLEN * 4;

    // ---- per-lane x staging source: lane l owns window word l ----
    // word layout: [s=l>>3][arr=(l>>2)&1][c=l&3], c==3 duplicates c==2.
    const int sW = lane >> 3, arrW = (lane >> 2) & 1, cW = lane & 3;
    const float* xsrc = (arrW ? magp : accp) + sW * 3 + (cW < 3 ? cW : 2);

    // prologue: windows 0 and 1
    {
        float x0 = xsrc[0];
        float x1 = xsrc[24];
        xwin[0][lane] = x0;
        xwin[1][lane] = x1;
    }

    float h = 0.0f;                  // this lane's h_j

    // ---- one GRU step: read h_{t-1} from slot sp, write h_t to slot ss ----
    auto step = [&](int sp, int ss, float a0, float a1, float a2,
                                    float m0, float m1, float m2) {
        const float* hb = &hbuf[sp * HID + kb];
        f4v A = *reinterpret_cast<const f4v*>(hb + 0);   // broadcast ds_read_b128 x4
        f4v B = *reinterpret_cast<const f4v*>(hb + 4);
        f4v C = *reinterpret_cast<const f4v*>(hb + 8);
        f4v D = *reinterpret_cast<const f4v*>(hb + 12);
        f2 hp[8] = { {A.x,A.y},{A.z,A.w},{B.x,B.y},{B.z,B.w},
                     {C.x,C.y},{C.z,C.w},{D.x,D.y},{D.z,D.w} };

        f2 dr0 = wr[0] * hp[0]; f2 dr1 = wr[4] * hp[4];
        f2 dz0 = wz[0] * hp[0]; f2 dz1 = wz[4] * hp[4];
        f2 dn0 = wn[0] * hp[0]; f2 dn1 = wn[4] * hp[4];
#pragma unroll
        for (int p = 1; p < 4; ++p) {
            dr0 += wr[p] * hp[p];  dr1 += wr[p + 4] * hp[p + 4];
            dz0 += wz[p] * hp[p];  dz1 += wz[p + 4] * hp[p + 4];
            dn0 += wn[p] * hp[p];  dn1 += wn[p + 4] * hp[p + 4];
        }

        // input-gate chains (independent of h -> fills LDS-read latency)
        float gr = fmaf(a2, wir[2], fmaf(a1, wir[1], fmaf(a0, wir[0], br_s)));
        gr = fmaf(m2, wir[5], fmaf(m1, wir[4], fmaf(m0, wir[3], gr)));
        float gz = fmaf(a2, wiz[2], fmaf(a1, wiz[1], fmaf(a0, wiz[0], bz_s)));
        gz = fmaf(m2, wiz[5], fmaf(m1, wiz[4], fmaf(m0, wiz[3], gz)));
        float gn = fmaf(a2, win[2], fmaf(a1, win[1], fmaf(a0, win[0], bin_s)));
        gn = fmaf(m2, win[5], fmaf(m1, win[4], fmaf(m0, win[3], gn)));

        // horizontal + cross-half combine (permlane32_swap: VALU, not DS)
        f2 drs = dr0 + dr1; float sr = drs.x + drs.y + gr;
        f2 dzs = dz0 + dz1; float sz = dzs.x + dzs.y + gz;
        f2 dns = dn0 + dn1; float hn = dns.x + dns.y + bhn_s;
        sr = xor32_sum(sr);
        sz = xor32_sum(sz);
        hn = xor32_sum(hn);

        // gates; weights pre-scaled so exp2 needs no input multiply
        float r = fast_rcp(1.0f + fast_exp2(-sr));
        float z = fast_rcp(1.0f + fast_exp2(-sz));
        float ap = fmaf(r, hn, gn);
        ap = fmaxf(ap, -30.0f);
        float u  = fast_exp2(-ap);
        float nn = (1.0f - u) * fast_rcp(1.0f + u);    // tanh
        h = fmaf(z, h - nn, nn);                       // (1-z)*n + z*h
        hbuf[ss * HID + j] = h;
    };

    // ---- q-head for 8 timesteps at once, from the h history ring ----
    auto qbatch = [&](int t0) {
        const float* hq = &hbuf[tq * HID + kq * 16];
        f4v QA = *reinterpret_cast<const f4v*>(hq + 0);
        f4v QB = *reinterpret_cast<const f4v*>(hq + 4);
        f4v QC = *reinterpret_cast<const f4v*>(hq + 8);
        f4v QD = *reinterpret_cast<const f4v*>(hq + 12);
        f4v qa = QA * wq4[0];
        qa += QB * wq4[1];
        qa += QC * wq4[2];
        qa += QD * wq4[3];
        float qp = (qa.x + qa.y) + (qa.z + qa.w);
        qp += SWZ_XOR(qp, 4);            // combine K-halves (lanes l^4)
        qp += bqv;
        float s = qp * qp;
        s += SWZ_XOR(s, 1);
        s += SWZ_XOR(s, 2);              // sum of 4 squared components
        float qv = qp * fast_rsq(s);
        if (!(lane & 4))                 // kq==0 lanes: 32 coalesced floats
            outp[(size_t)(t0 + tq) * 4 + m] = qv;
    };

    // ---- main loop: 256 windows of 8 steps ----
    for (int w = 0; w < NWIN; ++w) {
        // ISSUE EARLY: global load of window w+2's word (use is the ds_write
        // at the bottom -> ~8 steps of latency cover under vmcnt).
        const int tn = (w + 2 < NWIN) ? (w + 2) * 24 : 0;
        const float xstage = xsrc[tn];

        const float* xw = &xwin[w & 1][0];
#pragma unroll
        for (int s = 0; s < 8; ++s) {
            f4v xa = *reinterpret_cast<const f4v*>(xw + 8 * s);     // acc trio (+dup)
            f4v xm = *reinterpret_cast<const f4v*>(xw + 8 * s + 4); // mag trio (+dup)
            step((s + 7) & 7, s, xa.x, xa.y, xa.z, xm.x, xm.y, xm.z);
        }
        qbatch(w * 8);

        // WRITE LATE: buffer w&1 fully consumed; park window w+2 there.
        xwin[w & 1][lane] = xstage;
    }
}

extern "C" void kernel_launch(void* const* d_in, const int* in_sizes, int n_in,
                              void* d_out, int out_size, void* d_ws, size_t ws_size,
                              hipStream_t stream) {
    const float* acc  = (const float*)d_in[0];
    const float* mag  = (const float*)d_in[1];
    const float* W_ih = (const float*)d_in[2];
    const float* W_hh = (const float*)d_in[3];
    const float* b_ih = (const float*)d_in[4];
    const float* b_hh = (const float*)d_in[5];
    const float* Wq   = (const float*)d_in[6];
    const float* bq   = (const float*)d_in[7];

    gru_fused_kernel<<<dim3(BATCH), dim3(64), 0, stream>>>(
        acc, mag, W_ih, W_hh, b_ih, b_hh, Wq, bq, (float*)d_out);
}